// Round 3
// baseline (454.694 us; speedup 1.0000x reference)
//
#include <hip/hip_runtime.h>
#include <hip/hip_bf16.h>

// Reference returns (input0, input1) unchanged — the vmap'd scan is dead code.
// d_out = concat(input0.flat, input1.flat), each 2048*65536 f32 elements.
// Pure memory-bound copy: 1 GiB in + 1 GiB out => ~341 us at 6.3 TB/s.
//
// R1: 452 us (4.74 TB/s eff), two sequential loops, cached accesses.
// R2: nontemporal builtins reject HIP_vector_type (class, not vector) —
//     use native clang ext_vector_type(4) float for the ld/st pointers.

typedef float f32x4 __attribute__((ext_vector_type(4)));

__global__ __launch_bounds__(256) void concat_copy_kernel(
    const f32x4* __restrict__ a,
    const f32x4* __restrict__ b,
    f32x4* __restrict__ out,
    long n4) {  // n4 = f32x4 count per input
    long tid = (long)blockIdx.x * blockDim.x + threadIdx.x;
    long stride = (long)gridDim.x * blockDim.x;
    #pragma unroll 2
    for (long k = tid; k < n4; k += stride) {
        f32x4 va = __builtin_nontemporal_load(&a[k]);
        f32x4 vb = __builtin_nontemporal_load(&b[k]);
        __builtin_nontemporal_store(va, &out[k]);
        __builtin_nontemporal_store(vb, &out[n4 + k]);
    }
}

extern "C" void kernel_launch(void* const* d_in, const int* in_sizes, int n_in,
                              void* d_out, int out_size, void* d_ws, size_t ws_size,
                              hipStream_t stream) {
    const f32x4* in0 = (const f32x4*)d_in[0];
    const f32x4* in1 = (const f32x4*)d_in[1];
    f32x4* out = (f32x4*)d_out;

    long n = (long)in_sizes[0];       // 2048*65536 = 134217728, divisible by 4
    long n4 = n / 4;                  // 33554432 f32x4 per input

    const int block = 256;
    const int grid = 2048;            // 256 CUs * 8 blocks/CU; 64 iters/thread exactly

    concat_copy_kernel<<<grid, block, 0, stream>>>(in0, in1, out, n4);
}